// Round 4
// baseline (209.045 us; speedup 1.0000x reference)
//
#include <hip/hip_runtime.h>
#include <hip/hip_cooperative_groups.h>
#include <math.h>

namespace cg = cooperative_groups;

#define B_ 4
#define T_ 512
#define D_ 64
#define EPS 1e-8f

__device__ __forceinline__ float wave_sum(float v) {
#pragma unroll
  for (int m = 1; m < 64; m <<= 1) v += __shfl_xor(v, m, 64);
  return v;
}
__device__ __forceinline__ float softplus_f(float x) {
  return fmaxf(x, 0.0f) + log1pf(expf(-fabsf(x)));
}

#define DOT4(ACC, A, Bv) \
  ACC = fmaf((A).x, (Bv).x, fmaf((A).y, (Bv).y, fmaf((A).z, (Bv).z, fmaf((A).w, (Bv).w, ACC))))

// Stage 512x64 f32 (row-major, stride 64) global -> LDS with XOR swizzle.
// LDS physical (j, c4) holds logical (j, c4 ^ ((j>>2)&7)); reader of logical
// (j, d4) reads physical d4 ^ ((j>>2)&7).
__device__ __forceinline__ void stage512(const float* __restrict__ g,
                                         float* __restrict__ lds, int tid) {
#pragma unroll
  for (int h = 0; h < 2; ++h) {
    float4 v[8];
#pragma unroll
    for (int r = 0; r < 8; ++r) {
      int slot = (h * 8 + r) * 512 + tid;
      int j = slot >> 4, c4 = slot & 15;
      v[r] = *(const float4*)(g + j * 64 + ((c4 ^ ((j >> 2) & 7)) << 2));
    }
#pragma unroll
    for (int r = 0; r < 8; ++r) {
      int slot = (h * 8 + r) * 512 + tid;
      int j = slot >> 4, c4 = slot & 15;
      *(float4*)(lds + j * 64 + (c4 << 2)) = v[r];
    }
  }
}

// ---- one attention iteration: logits + softmax + w@x + residual (+ next s) ----
// Caller guarantees a full barrier (grid.sync) before entry.
__device__ __forceinline__ void fiter_body(
    const float* __restrict__ sb, const float* __restrict__ xb,
    float* __restrict__ xoutb, float* __restrict__ soutb, int i0, int tid,
    float c01, float* __restrict__ sx, float* __restrict__ wlds,
    float* __restrict__ redv, float* __restrict__ redM,
    float* __restrict__ redS, int write_s) {
  int w = tid >> 6, lane = tid & 63;

  stage512(sb, sx, tid);
  __syncthreads();

  // ---- phase L: logits S = -2*acos(clip(s_i . s_j)) for 8 rows x 64 cols ----
  int i4 = lane >> 4, j16 = lane & 15;
  int ia0 = i0 + 2 * i4;
  const float* A0 = sx + ia0 * 64;
  const float* A1 = A0 + 64;
  int mA0 = (ia0 >> 2) & 7, mA1 = ((ia0 + 1) >> 2) & 7;
  const float* Bp = sx + (w * 64 + 4 * j16) * 64;  // 4 consecutive j rows
  int mB = j16 & 7;

  float acc[2][4];
#pragma unroll
  for (int r = 0; r < 2; ++r)
#pragma unroll
    for (int c = 0; c < 4; ++c) acc[r][c] = 0.f;

#pragma unroll
  for (int d4 = 0; d4 < 16; ++d4) {
    float4 a0 = *(const float4*)(A0 + ((d4 ^ mA0) << 2));
    float4 a1 = *(const float4*)(A1 + ((d4 ^ mA1) << 2));
    int ob = (d4 ^ mB) << 2;
    float4 b0 = *(const float4*)(Bp + ob);
    float4 b1 = *(const float4*)(Bp + 64 + ob);
    float4 b2 = *(const float4*)(Bp + 128 + ob);
    float4 b3 = *(const float4*)(Bp + 192 + ob);
    DOT4(acc[0][0], a0, b0); DOT4(acc[0][1], a0, b1);
    DOT4(acc[0][2], a0, b2); DOT4(acc[0][3], a0, b3);
    DOT4(acc[1][0], a1, b0); DOT4(acc[1][1], a1, b1);
    DOT4(acc[1][2], a1, b2); DOT4(acc[1][3], a1, b3);
  }

  float S[2][4];
#pragma unroll
  for (int r = 0; r < 2; ++r)
#pragma unroll
    for (int c = 0; c < 4; ++c) {
      float inner = fminf(fmaxf(acc[r][c], -1.0f + 1e-6f), 1.0f - 1e-6f);
      S[r][c] = -2.0f * acosf(inner);
    }

  // per-wave rowmax over 64 cols (reduce across j16 = lane bits 0..3)
  float m0 = fmaxf(fmaxf(S[0][0], S[0][1]), fmaxf(S[0][2], S[0][3]));
  float m1 = fmaxf(fmaxf(S[1][0], S[1][1]), fmaxf(S[1][2], S[1][3]));
#pragma unroll
  for (int mm = 1; mm < 16; mm <<= 1) {
    m0 = fmaxf(m0, __shfl_xor(m0, mm, 64));
    m1 = fmaxf(m1, __shfl_xor(m1, mm, 64));
  }
  if (j16 == 0) { redM[(2 * i4) * 8 + w] = m0; redM[(2 * i4 + 1) * 8 + w] = m1; }
  __syncthreads();  // all waves done reading sx (s) + redM complete

  // re-stage x into the (now dead) s region; latency overlaps softmax finish
  stage512(xb, sx, tid);

  float M0 = redM[(2 * i4) * 8], M1 = redM[(2 * i4 + 1) * 8];
#pragma unroll
  for (int q = 1; q < 8; ++q) {
    M0 = fmaxf(M0, redM[(2 * i4) * 8 + q]);
    M1 = fmaxf(M1, redM[(2 * i4 + 1) * 8 + q]);
  }
  float e[2][4];
  float sl0 = 0.f, sl1 = 0.f;
#pragma unroll
  for (int c = 0; c < 4; ++c) {
    e[0][c] = __expf(S[0][c] - M0); sl0 += e[0][c];
    e[1][c] = __expf(S[1][c] - M1); sl1 += e[1][c];
  }
#pragma unroll
  for (int mm = 1; mm < 16; mm <<= 1) {
    sl0 += __shfl_xor(sl0, mm, 64);
    sl1 += __shfl_xor(sl1, mm, 64);
  }
  if (j16 == 0) { redS[(2 * i4) * 8 + w] = sl0; redS[(2 * i4 + 1) * 8 + w] = sl1; }
  int wb = w * 64 + 4 * j16;
#pragma unroll
  for (int r = 0; r < 2; ++r)
#pragma unroll
    for (int c = 0; c < 4; ++c) wlds[(2 * i4 + r) * 516 + wb + c] = e[r][c];
  __syncthreads();  // x staged + wlds/redS complete

  // ---- phase P: xa[i][d] = sum_j e[i][j] * x[j][d] ----
  int js = tid & 15, dg = (tid >> 4) & 15, ig = tid >> 8;
  int xcol = ((dg ^ (js & 7)) << 2);
  float pacc[4][4];
#pragma unroll
  for (int ii = 0; ii < 4; ++ii)
#pragma unroll
    for (int k = 0; k < 4; ++k) pacc[ii][k] = 0.f;

#pragma unroll 2
  for (int jj = 0; jj < 8; ++jj) {
    int jbase = jj * 64 + js * 4;
    const float* xr = sx + jbase * 64 + xcol;
    float4 x0 = *(const float4*)(xr);
    float4 x1 = *(const float4*)(xr + 64);
    float4 x2 = *(const float4*)(xr + 128);
    float4 x3 = *(const float4*)(xr + 192);
#pragma unroll
    for (int ii = 0; ii < 4; ++ii) {
      float4 wv = *(const float4*)(wlds + (4 * ig + ii) * 516 + jbase);
      pacc[ii][0] = fmaf(wv.x, x0.x, fmaf(wv.y, x1.x, fmaf(wv.z, x2.x, fmaf(wv.w, x3.x, pacc[ii][0]))));
      pacc[ii][1] = fmaf(wv.x, x0.y, fmaf(wv.y, x1.y, fmaf(wv.z, x2.y, fmaf(wv.w, x3.y, pacc[ii][1]))));
      pacc[ii][2] = fmaf(wv.x, x0.z, fmaf(wv.y, x1.z, fmaf(wv.z, x2.z, fmaf(wv.w, x3.z, pacc[ii][2]))));
      pacc[ii][3] = fmaf(wv.x, x0.w, fmaf(wv.y, x1.w, fmaf(wv.z, x2.w, fmaf(wv.w, x3.w, pacc[ii][3]))));
    }
  }
#pragma unroll
  for (int ii = 0; ii < 4; ++ii)
#pragma unroll
    for (int k = 0; k < 4; ++k) {
      float v = pacc[ii][k];
      v += __shfl_xor(v, 1, 64);
      v += __shfl_xor(v, 2, 64);
      v += __shfl_xor(v, 4, 64);
      v += __shfl_xor(v, 8, 64);
      pacc[ii][k] = v;
    }
  if (js == 0) {
#pragma unroll
    for (int ii = 0; ii < 4; ++ii)
      *(float4*)(redv + (4 * ig + ii) * 68 + (dg << 2)) =
          make_float4(pacc[ii][0], pacc[ii][1], pacc[ii][2], pacc[ii][3]);
  }
  __syncthreads();

  // ---- final: normalize, residual, write x (+ fused next-iter s, per-row) ----
  {
    int row = w, d = lane;
    float ssum = 0.f;
#pragma unroll
    for (int q = 0; q < 8; ++q) ssum += redS[row * 8 + q];
    float xa = redv[row * 68 + d] / ssum;
    int ir = i0 + row;
    int mr = (ir >> 2) & 7;
    float xv = sx[ir * 64 + (((d >> 2) ^ mr) << 2) + (d & 3)];
    float xn = 0.5f * (1.0f - c01) * xv + 0.5f * (1.0f + c01) * xa;
    xoutb[ir * 64 + d] = xn;
    if (write_s) {
      float sp = softplus_f(xn);
      float s1 = wave_sum(sp);
      float p = sp / (s1 + EPS);
      p = fmaxf(p, EPS);
      float s2 = wave_sum(p);
      soutb[ir * 64 + d] = sqrtf(p / (s2 + EPS));
    }
  }
}

// ---- single cooperative launch: proj | iter1 | iter2 | p1 | p2 ----
__global__ __launch_bounds__(512) void mega_kernel(
    const float* __restrict__ x0, const float* __restrict__ rsp,
    float* __restrict__ out, float* __restrict__ s0, float* __restrict__ x1,
    float* __restrict__ s1, float* __restrict__ covp,
    float* __restrict__ meanp, float* __restrict__ kappap) {
  cg::grid_group grid = cg::this_grid();
  int bid = blockIdx.x, tid = threadIdx.x;
  int w = tid >> 6, lane = tid & 63;

  __shared__ __align__(16) float sx[512 * 64];
  __shared__ __align__(16) float wlds[8 * 516];
  __shared__ __align__(16) float redv[8 * 68];
  __shared__ float redM[64];
  __shared__ float redS[64];

  // ---- phase 0 (proj): s0 for 8 rows per block, one row per wave ----
  {
    int row = bid * 8 + w;  // 0..2047 over (b,t)
    float sp = softplus_f(x0[row * 64 + lane]);
    float s1v = wave_sum(sp);
    float p = sp / (s1v + EPS);
    p = fmaxf(p, EPS);
    float s2v = wave_sum(p);
    s0[row * 64 + lane] = sqrtf(p / (s2v + EPS));
  }
  grid.sync();

  float c01 = 0.01f * rsp[0];
  int b = bid >> 6, i0 = (bid & 63) * 8;
  size_t boff = (size_t)b * (T_ * D_);

  // ---- iter 1: (s0, x0) -> x1, s1 ----
  fiter_body(s0 + boff, x0 + boff, x1 + boff, s1 + boff, i0, tid, c01, sx,
             wlds, redv, redM, redS, 1);
  grid.sync();

  // ---- iter 2: (s1, x1) -> out (no s needed) ----
  fiter_body(s1 + boff, x1 + boff, out + boff, (float*)0, i0, tid, c01, sx,
             wlds, redv, redM, redS, 0);
  grid.sync();

  // ---- p1: 128 blocks, 16-row slices of out -> covp/meanp/kappap ----
  // stats scratch aliases the (dead) sx region
  float* tile = sx;            // [16][68] -> 1088 floats
  float* red2 = sx + 1152;     // 4*64
  float* kred = sx + 1408;     // 4
  float* mu = sx + 1472;       // 64
  float* var = sx + 1536;      // 64
  float* phired = sx + 1600;   // 8
  if (bid < 128) {
    const float* xb = out + (size_t)bid * (16 * D_);
    if (tid < 256) {
      int row = tid >> 4, c4 = tid & 15;
      *(float4*)&tile[row * 68 + c4 * 4] = *(const float4*)(xb + row * 64 + c4 * 4);
    }
    __syncthreads();

    if (tid < 256) {
      // kappa partial (waves 0..3)
      int tr = tid >> 4, qq = tid & 15;
      float ksq = 0.f;
#pragma unroll
      for (int k = 0; k < 4; ++k) {
        float v = tile[tr * 68 + qq * 4 + k];
        ksq = fmaf(v, v, ksq);
      }
      ksq += __shfl_xor(ksq, 1, 64);
      ksq += __shfl_xor(ksq, 2, 64);
      ksq += __shfl_xor(ksq, 4, 64);
      ksq += __shfl_xor(ksq, 8, 64);
      float contrib = (qq == 0) ? sqrtf(ksq) : 0.f;
      contrib = wave_sum(contrib);
      if ((tid & 63) == 0) kred[tid >> 6] = contrib;
      // mean partial
      int d = tid & 63, q = tid >> 6;
      float ms = 0.f;
#pragma unroll
      for (int tt = 0; tt < 4; ++tt) ms += tile[(q * 4 + tt) * 68 + d];
      red2[q * 64 + d] = ms;
    }

    // cov partial with all 512 threads: (dd 0..63, e8 0..7)
    {
      int dd = tid >> 3, e8 = tid & 7;
      float acc[8];
#pragma unroll
      for (int k = 0; k < 8; ++k) acc[k] = 0.f;
#pragma unroll
      for (int tt = 0; tt < 16; ++tt) {
        float xd = tile[tt * 68 + dd];
        float4 v0 = *(const float4*)&tile[tt * 68 + e8 * 8];
        float4 v1 = *(const float4*)&tile[tt * 68 + e8 * 8 + 4];
        acc[0] = fmaf(xd, v0.x, acc[0]); acc[1] = fmaf(xd, v0.y, acc[1]);
        acc[2] = fmaf(xd, v0.z, acc[2]); acc[3] = fmaf(xd, v0.w, acc[3]);
        acc[4] = fmaf(xd, v1.x, acc[4]); acc[5] = fmaf(xd, v1.y, acc[5]);
        acc[6] = fmaf(xd, v1.z, acc[6]); acc[7] = fmaf(xd, v1.w, acc[7]);
      }
      float* cp = covp + (size_t)bid * 4096 + dd * 64 + e8 * 8;
      *(float4*)(cp) = make_float4(acc[0], acc[1], acc[2], acc[3]);
      *(float4*)(cp + 4) = make_float4(acc[4], acc[5], acc[6], acc[7]);
    }
    __syncthreads();
    if (tid < 64)
      meanp[bid * 64 + tid] =
          red2[tid] + red2[64 + tid] + red2[128 + tid] + red2[192 + tid];
    if (tid == 0) kappap[bid] = kred[0] + kred[1] + kred[2] + kred[3];
  }
  grid.sync();

  // ---- p2: 4 blocks (one per batch) finalize phi + kappa ----
  if (bid < B_) {
    int bb = bid;
    if (tid < 64) {
      float m = 0.f;
#pragma unroll
      for (int s = 0; s < 32; ++s) m += meanp[(bb * 32 + s) * 64 + tid];
      mu[tid] = m * (1.0f / 512.0f);
    }
    __syncthreads();

    int dd = tid >> 3, e8 = tid & 7;
    float acc[8];
#pragma unroll
    for (int k = 0; k < 8; ++k) acc[k] = 0.f;
#pragma unroll
    for (int s = 0; s < 32; ++s) {
      const float* cp = covp + (size_t)(bb * 32 + s) * 4096 + dd * 64 + e8 * 8;
      float4 v0 = *(const float4*)(cp);
      float4 v1 = *(const float4*)(cp + 4);
      acc[0] += v0.x; acc[1] += v0.y; acc[2] += v0.z; acc[3] += v0.w;
      acc[4] += v1.x; acc[5] += v1.y; acc[6] += v1.z; acc[7] += v1.w;
    }
    float mud = mu[dd];
#pragma unroll
    for (int k = 0; k < 8; ++k)
      acc[k] = acc[k] * (1.0f / 512.0f) - mud * mu[e8 * 8 + k];  // cov
    if (e8 == (dd >> 3)) var[dd] = fmaxf(acc[dd & 7], EPS);
    __syncthreads();

    float vd = var[dd];
    float psum = 0.f;
#pragma unroll
    for (int k = 0; k < 8; ++k) {
      int e = e8 * 8 + k;
      if (e == dd) continue;
      float denom = fmaxf(sqrtf(vd * var[e]), EPS);
      float cc = fminf(fmaxf(acc[k] / denom, -1.0f), 1.0f);
      psum += fabsf(cc);
    }
    psum = wave_sum(psum);
    if ((tid & 63) == 0) phired[tid >> 6] = psum;
    __syncthreads();
    if (tid == 0) {
      float ph = 0.f;
#pragma unroll
      for (int q = 0; q < 8; ++q) ph += phired[q];
      out[B_ * T_ * D_ + bb] = ph * (1.0f / 4096.0f);
      float ks = 0.f;
#pragma unroll
      for (int s = 0; s < 32; ++s) ks += kappap[bb * 32 + s];
      out[B_ * T_ * D_ + B_ + bb] = ks * (1.0f / 512.0f);
    }
  }
}

extern "C" void kernel_launch(void* const* d_in, const int* in_sizes, int n_in,
                              void* d_out, int out_size, void* d_ws, size_t ws_size,
                              hipStream_t stream) {
  const float* x0 = (const float*)d_in[0];
  const float* rs = (const float*)d_in[1];
  float* out = (float*)d_out;
  float* s0 = (float*)d_ws;          // 131072 floats
  float* x1 = s0 + B_ * T_ * D_;     // 131072
  float* s1 = x1 + B_ * T_ * D_;     // 131072
  float* covp = s1 + B_ * T_ * D_;   // 128*4096
  float* meanp = covp + 128 * 4096;  // 128*64
  float* kappap = meanp + 128 * 64;  // 128

  void* args[] = {(void*)&x0,   (void*)&rs,    (void*)&out,
                  (void*)&s0,   (void*)&x1,    (void*)&s1,
                  (void*)&covp, (void*)&meanp, (void*)&kappap};
  hipLaunchCooperativeKernel((const void*)mega_kernel, dim3(256), dim3(512),
                             args, 0, stream);
}

// Round 5
// 116.196 us; speedup vs baseline: 1.7991x; 1.7991x over previous
//
#include <hip/hip_runtime.h>
#include <math.h>

#define B_ 4
#define T_ 512
#define D_ 64
#define EPS 1e-8f

__device__ __forceinline__ float wave_sum(float v) {
#pragma unroll
  for (int m = 1; m < 64; m <<= 1) v += __shfl_xor(v, m, 64);
  return v;
}
__device__ __forceinline__ float softplus_f(float x) {
  return fmaxf(x, 0.0f) + log1pf(expf(-fabsf(x)));
}

#define DOT4(ACC, A, Bv) \
  ACC = fmaf((A).x, (Bv).x, fmaf((A).y, (Bv).y, fmaf((A).z, (Bv).z, fmaf((A).w, (Bv).w, ACC))))

// ---- s = sqrt(double-normalized softplus simplex); also zeroes ticket cnt ----
__global__ __launch_bounds__(256) void proj_kernel(const float* __restrict__ x,
                                                   float* __restrict__ s,
                                                   unsigned int* __restrict__ cnt) {
  if (blockIdx.x == 0 && threadIdx.x < B_) cnt[threadIdx.x] = 0u;
  int wave = threadIdx.x >> 6, lane = threadIdx.x & 63;
  int row = blockIdx.x * 4 + wave;  // (b,t) flat
  float sp = softplus_f(x[row * D_ + lane]);
  float s1 = wave_sum(sp);
  float p = sp / (s1 + EPS);
  p = fmaxf(p, EPS);
  float s2 = wave_sum(p);
  s[row * D_ + lane] = sqrtf(p / (s2 + EPS));
}

// Stage 512x64 f32 (row-major, stride 64) global -> LDS with XOR swizzle.
// LDS physical (j, c4) holds logical (j, c4 ^ ((j>>2)&7)); reader of logical
// (j, d4) reads physical d4 ^ ((j>>2)&7).
__device__ __forceinline__ void stage512(const float* __restrict__ g,
                                         float* __restrict__ lds, int tid) {
#pragma unroll
  for (int h = 0; h < 2; ++h) {
    float4 v[8];
#pragma unroll
    for (int r = 0; r < 8; ++r) {
      int slot = (h * 8 + r) * 512 + tid;
      int j = slot >> 4, c4 = slot & 15;
      v[r] = *(const float4*)(g + j * 64 + ((c4 ^ ((j >> 2) & 7)) << 2));
    }
#pragma unroll
    for (int r = 0; r < 8; ++r) {
      int slot = (h * 8 + r) * 512 + tid;
      int j = slot >> 4, c4 = slot & 15;
      *(float4*)(lds + j * 64 + (c4 << 2)) = v[r];
    }
  }
}

// ---- fused iteration: logits + softmax + w@x + residual (+ fused next-iter s) ----
// Block: 8 query rows, 512 threads (8 waves). Grid (64, B).
template <int WRITE_S>
__global__ __launch_bounds__(512) void fiter_kernel(const float* __restrict__ s_g,
                                                    const float* __restrict__ x_g,
                                                    const float* __restrict__ rsp,
                                                    float* __restrict__ xout,
                                                    float* __restrict__ sout) {
  int b = blockIdx.y, i0 = blockIdx.x * 8;
  int tid = threadIdx.x;
  int w = tid >> 6, lane = tid & 63;
  const float* sb = s_g + (size_t)b * (T_ * D_);
  const float* xb = x_g + (size_t)b * (T_ * D_);

  __shared__ __align__(16) float sx[512 * 64];   // s, then re-staged as x
  __shared__ __align__(16) float wlds[8 * 516];  // unnormalized exp weights
  __shared__ __align__(16) float redv[8 * 68];   // per-(row,d) PV partial
  __shared__ float redM[8][8];                   // rowmax partial [row][wave]
  __shared__ float redS[8][8];                   // exp-sum partial [row][wave]

  stage512(sb, sx, tid);
  __syncthreads();

  // ---- phase L: logits S = -2*acos(clip(s_i . s_j)) for 8 rows x 64 cols ----
  int i4 = lane >> 4, j16 = lane & 15;
  int ia0 = i0 + 2 * i4;
  const float* A0 = sx + ia0 * 64;
  const float* A1 = A0 + 64;
  int mA0 = (ia0 >> 2) & 7, mA1 = ((ia0 + 1) >> 2) & 7;
  const float* Bp = sx + (w * 64 + 4 * j16) * 64;  // 4 consecutive j rows
  int mB = j16 & 7;

  float acc[2][4];
#pragma unroll
  for (int r = 0; r < 2; ++r)
#pragma unroll
    for (int c = 0; c < 4; ++c) acc[r][c] = 0.f;

#pragma unroll
  for (int d4 = 0; d4 < 16; ++d4) {
    float4 a0 = *(const float4*)(A0 + ((d4 ^ mA0) << 2));
    float4 a1 = *(const float4*)(A1 + ((d4 ^ mA1) << 2));
    int ob = (d4 ^ mB) << 2;
    float4 b0 = *(const float4*)(Bp + ob);
    float4 b1 = *(const float4*)(Bp + 64 + ob);
    float4 b2 = *(const float4*)(Bp + 128 + ob);
    float4 b3 = *(const float4*)(Bp + 192 + ob);
    DOT4(acc[0][0], a0, b0); DOT4(acc[0][1], a0, b1);
    DOT4(acc[0][2], a0, b2); DOT4(acc[0][3], a0, b3);
    DOT4(acc[1][0], a1, b0); DOT4(acc[1][1], a1, b1);
    DOT4(acc[1][2], a1, b2); DOT4(acc[1][3], a1, b3);
  }

  float S[2][4];
#pragma unroll
  for (int r = 0; r < 2; ++r)
#pragma unroll
    for (int c = 0; c < 4; ++c) {
      float inner = fminf(fmaxf(acc[r][c], -1.0f + 1e-6f), 1.0f - 1e-6f);
      S[r][c] = -2.0f * acosf(inner);
    }

  // per-wave rowmax over 64 cols (reduce across j16 = lane bits 0..3)
  float m0 = fmaxf(fmaxf(S[0][0], S[0][1]), fmaxf(S[0][2], S[0][3]));
  float m1 = fmaxf(fmaxf(S[1][0], S[1][1]), fmaxf(S[1][2], S[1][3]));
#pragma unroll
  for (int mm = 1; mm < 16; mm <<= 1) {
    m0 = fmaxf(m0, __shfl_xor(m0, mm, 64));
    m1 = fmaxf(m1, __shfl_xor(m1, mm, 64));
  }
  if (j16 == 0) { redM[2 * i4][w] = m0; redM[2 * i4 + 1][w] = m1; }
  __syncthreads();  // all waves done reading sx (s) + redM complete

  // re-stage x into the (now dead) s region; latency overlaps softmax finish
  stage512(xb, sx, tid);

  float M0 = redM[2 * i4][0], M1 = redM[2 * i4 + 1][0];
#pragma unroll
  for (int q = 1; q < 8; ++q) {
    M0 = fmaxf(M0, redM[2 * i4][q]);
    M1 = fmaxf(M1, redM[2 * i4 + 1][q]);
  }
  float e[2][4];
  float sl0 = 0.f, sl1 = 0.f;
#pragma unroll
  for (int c = 0; c < 4; ++c) {
    e[0][c] = __expf(S[0][c] - M0); sl0 += e[0][c];
    e[1][c] = __expf(S[1][c] - M1); sl1 += e[1][c];
  }
#pragma unroll
  for (int mm = 1; mm < 16; mm <<= 1) {
    sl0 += __shfl_xor(sl0, mm, 64);
    sl1 += __shfl_xor(sl1, mm, 64);
  }
  if (j16 == 0) { redS[2 * i4][w] = sl0; redS[2 * i4 + 1][w] = sl1; }
  int wb = w * 64 + 4 * j16;
#pragma unroll
  for (int r = 0; r < 2; ++r)
#pragma unroll
    for (int c = 0; c < 4; ++c) wlds[(2 * i4 + r) * 516 + wb + c] = e[r][c];
  __syncthreads();  // x staged + wlds/redS complete

  // ---- phase P: xa[i][d] = sum_j e[i][j] * x[j][d] ----
  int js = tid & 15, dg = (tid >> 4) & 15, ig = tid >> 8;
  int xcol = ((dg ^ (js & 7)) << 2);
  float pacc[4][4];
#pragma unroll
  for (int ii = 0; ii < 4; ++ii)
#pragma unroll
    for (int k = 0; k < 4; ++k) pacc[ii][k] = 0.f;

#pragma unroll 2
  for (int jj = 0; jj < 8; ++jj) {
    int jbase = jj * 64 + js * 4;
    const float* xr = sx + jbase * 64 + xcol;
    float4 x0 = *(const float4*)(xr);
    float4 x1 = *(const float4*)(xr + 64);
    float4 x2 = *(const float4*)(xr + 128);
    float4 x3 = *(const float4*)(xr + 192);
#pragma unroll
    for (int ii = 0; ii < 4; ++ii) {
      float4 wv = *(const float4*)(wlds + (4 * ig + ii) * 516 + jbase);
      pacc[ii][0] = fmaf(wv.x, x0.x, fmaf(wv.y, x1.x, fmaf(wv.z, x2.x, fmaf(wv.w, x3.x, pacc[ii][0]))));
      pacc[ii][1] = fmaf(wv.x, x0.y, fmaf(wv.y, x1.y, fmaf(wv.z, x2.y, fmaf(wv.w, x3.y, pacc[ii][1]))));
      pacc[ii][2] = fmaf(wv.x, x0.z, fmaf(wv.y, x1.z, fmaf(wv.z, x2.z, fmaf(wv.w, x3.z, pacc[ii][2]))));
      pacc[ii][3] = fmaf(wv.x, x0.w, fmaf(wv.y, x1.w, fmaf(wv.z, x2.w, fmaf(wv.w, x3.w, pacc[ii][3]))));
    }
  }
#pragma unroll
  for (int ii = 0; ii < 4; ++ii)
#pragma unroll
    for (int k = 0; k < 4; ++k) {
      float v = pacc[ii][k];
      v += __shfl_xor(v, 1, 64);
      v += __shfl_xor(v, 2, 64);
      v += __shfl_xor(v, 4, 64);
      v += __shfl_xor(v, 8, 64);
      pacc[ii][k] = v;
    }
  if (js == 0) {
#pragma unroll
    for (int ii = 0; ii < 4; ++ii)
      *(float4*)(redv + (4 * ig + ii) * 68 + (dg << 2)) =
          make_float4(pacc[ii][0], pacc[ii][1], pacc[ii][2], pacc[ii][3]);
  }
  __syncthreads();

  // ---- final: normalize, residual, write x (+ fused next-iter s) ----
  {
    int row = w, d = lane;
    float ssum = 0.f;
#pragma unroll
    for (int q = 0; q < 8; ++q) ssum += redS[row][q];
    float xa = redv[row * 68 + d] / ssum;
    int ir = i0 + row;
    int mr = (ir >> 2) & 7;
    float xv = sx[ir * 64 + (((d >> 2) ^ mr) << 2) + (d & 3)];
    float c01 = 0.01f * rsp[0];
    float xn = 0.5f * (1.0f - c01) * xv + 0.5f * (1.0f + c01) * xa;
    size_t gi = ((size_t)(b * T_) + ir) * D_ + d;
    xout[gi] = xn;
    if (WRITE_S) {
      float sp = softplus_f(xn);
      float s1 = wave_sum(sp);
      float p = sp / (s1 + EPS);
      p = fmaxf(p, EPS);
      float s2 = wave_sum(p);
      sout[gi] = sqrtf(p / (s2 + EPS));
    }
  }
}

// ---- stats: p1 partials per 16-row slice + last-block-per-batch finalize ----
__global__ __launch_bounds__(256) void stats_kernel(const float* __restrict__ x,
                                                    float* __restrict__ covp,
                                                    float* __restrict__ meanp,
                                                    float* __restrict__ kappap,
                                                    unsigned int* __restrict__ cnt,
                                                    float* __restrict__ out) {
  int blk = blockIdx.x;          // b*32 + slice
  int b = blk >> 5;
  const float* xb = x + (size_t)blk * (16 * D_);
  __shared__ float tile[16][68];
  __shared__ float red2[4][64];
  __shared__ float kred[4];
  __shared__ int lastflag;
  int tid = threadIdx.x;
  {
    int row = tid >> 4, c4 = tid & 15;
    *(float4*)&tile[row][c4 * 4] = *(const float4*)(xb + row * D_ + c4 * 4);
  }
  __syncthreads();

  // kappa partial
  {
    int tr = tid >> 4, qq = tid & 15;
    float ksq = 0.f;
#pragma unroll
    for (int k = 0; k < 4; ++k) {
      float v = tile[tr][qq * 4 + k];
      ksq = fmaf(v, v, ksq);
    }
    ksq += __shfl_xor(ksq, 1, 64);
    ksq += __shfl_xor(ksq, 2, 64);
    ksq += __shfl_xor(ksq, 4, 64);
    ksq += __shfl_xor(ksq, 8, 64);
    float contrib = (qq == 0) ? sqrtf(ksq) : 0.f;
    contrib = wave_sum(contrib);
    if ((tid & 63) == 0) kred[tid >> 6] = contrib;
  }

  // mean partial
  {
    int d = tid & 63, q = tid >> 6;
    float ms = 0.f;
#pragma unroll
    for (int tt = 0; tt < 4; ++tt) ms += tile[q * 4 + tt][d];
    red2[q][d] = ms;
  }

  // cov partial: thread (dd, e16)
  {
    int dd = tid >> 2, e16 = tid & 3;
    float acc[16];
#pragma unroll
    for (int k = 0; k < 16; ++k) acc[k] = 0.f;
#pragma unroll
    for (int tt = 0; tt < 16; ++tt) {
      float xd = tile[tt][dd];
      const float4* te = (const float4*)&tile[tt][e16 * 16];
      float4 v0 = te[0], v1 = te[1], v2 = te[2], v3 = te[3];
      acc[0]  = fmaf(xd, v0.x, acc[0]);  acc[1]  = fmaf(xd, v0.y, acc[1]);
      acc[2]  = fmaf(xd, v0.z, acc[2]);  acc[3]  = fmaf(xd, v0.w, acc[3]);
      acc[4]  = fmaf(xd, v1.x, acc[4]);  acc[5]  = fmaf(xd, v1.y, acc[5]);
      acc[6]  = fmaf(xd, v1.z, acc[6]);  acc[7]  = fmaf(xd, v1.w, acc[7]);
      acc[8]  = fmaf(xd, v2.x, acc[8]);  acc[9]  = fmaf(xd, v2.y, acc[9]);
      acc[10] = fmaf(xd, v2.z, acc[10]); acc[11] = fmaf(xd, v2.w, acc[11]);
      acc[12] = fmaf(xd, v3.x, acc[12]); acc[13] = fmaf(xd, v3.y, acc[13]);
      acc[14] = fmaf(xd, v3.z, acc[14]); acc[15] = fmaf(xd, v3.w, acc[15]);
    }
    float* cp = covp + (size_t)blk * 4096 + dd * 64 + e16 * 16;
#pragma unroll
    for (int kk = 0; kk < 4; ++kk)
      *(float4*)(cp + kk * 4) =
          make_float4(acc[kk * 4], acc[kk * 4 + 1], acc[kk * 4 + 2], acc[kk * 4 + 3]);
  }
  __syncthreads();
  if (tid < 64)
    meanp[blk * 64 + tid] = red2[0][tid] + red2[1][tid] + red2[2][tid] + red2[3][tid];
  if (tid == 0) kappap[blk] = kred[0] + kred[1] + kred[2] + kred[3];

  // ---- last-block-per-batch finalize (fused p2) ----
  __threadfence();
  __syncthreads();
  if (tid == 0) {
    unsigned int old = atomicAdd(&cnt[b], 1u);
    lastflag = (old == 31u);
  }
  __syncthreads();
  if (!lastflag) return;
  __threadfence();

  __shared__ float mu[64];
  __shared__ float var[64];
  __shared__ float phired[4];
  if (tid < 64) {
    float m = 0.f;
#pragma unroll
    for (int s = 0; s < 32; ++s) m += meanp[(b * 32 + s) * 64 + tid];
    mu[tid] = m * (1.0f / 512.0f);
  }
  __syncthreads();

  int dd = tid >> 2, e16 = tid & 3;  // 64 x 4, each thread 16 cells
  float acc[16];
#pragma unroll
  for (int k = 0; k < 16; ++k) acc[k] = 0.f;
#pragma unroll
  for (int s = 0; s < 32; ++s) {
    const float* cp = covp + (size_t)(b * 32 + s) * 4096 + dd * 64 + e16 * 16;
#pragma unroll
    for (int kk = 0; kk < 4; ++kk) {
      float4 v = *(const float4*)(cp + kk * 4);
      acc[kk * 4] += v.x; acc[kk * 4 + 1] += v.y;
      acc[kk * 4 + 2] += v.z; acc[kk * 4 + 3] += v.w;
    }
  }
  float mud = mu[dd];
#pragma unroll
  for (int k = 0; k < 16; ++k)
    acc[k] = acc[k] * (1.0f / 512.0f) - mud * mu[e16 * 16 + k];  // cov
  if (e16 == (dd >> 4)) var[dd] = fmaxf(acc[dd & 15], EPS);
  __syncthreads();

  float vd = var[dd];
  float psum = 0.f;
#pragma unroll
  for (int k = 0; k < 16; ++k) {
    int e = e16 * 16 + k;
    if (e == dd) continue;
    float denom = fmaxf(sqrtf(vd * var[e]), EPS);
    float cc = fminf(fmaxf(acc[k] / denom, -1.0f), 1.0f);
    psum += fabsf(cc);
  }
  psum = wave_sum(psum);
  if ((tid & 63) == 0) phired[tid >> 6] = psum;
  __syncthreads();
  if (tid == 0) {
    out[B_ * T_ * D_ + b] = (phired[0] + phired[1] + phired[2] + phired[3]) *
                            (1.0f / 4096.0f);
    float ks = 0.f;
#pragma unroll
    for (int s = 0; s < 32; ++s) ks += kappap[b * 32 + s];
    out[B_ * T_ * D_ + B_ + b] = ks * (1.0f / 512.0f);
  }
}

extern "C" void kernel_launch(void* const* d_in, const int* in_sizes, int n_in,
                              void* d_out, int out_size, void* d_ws, size_t ws_size,
                              hipStream_t stream) {
  const float* x0 = (const float*)d_in[0];
  const float* rs = (const float*)d_in[1];
  float* out = (float*)d_out;
  float* s0    = (float*)d_ws;                 // 131072 floats
  float* s1    = s0 + B_ * T_ * D_;            // 131072
  float* x1    = s1 + B_ * T_ * D_;            // 131072
  float* covp  = x1 + B_ * T_ * D_;            // 128*4096
  float* meanp = covp + 128 * 4096;            // 128*64
  float* kappap = meanp + 128 * 64;            // 128
  unsigned int* cnt = (unsigned int*)(kappap + 128);  // 4

  dim3 fgrd(64, 4);
  proj_kernel<<<(B_ * T_) / 4, 256, 0, stream>>>(x0, s0, cnt);
  fiter_kernel<1><<<fgrd, 512, 0, stream>>>(s0, x0, rs, x1, s1);
  fiter_kernel<0><<<fgrd, 512, 0, stream>>>(s1, x1, rs, out, (float*)0);
  stats_kernel<<<128, 256, 0, stream>>>(out, covp, meanp, kappap, cnt, out);
}

// Round 6
// 99.761 us; speedup vs baseline: 2.0955x; 1.1647x over previous
//
#include <hip/hip_runtime.h>
#include <math.h>

#define B_ 4
#define T_ 512
#define D_ 64
#define EPS 1e-8f

__device__ __forceinline__ float wave_sum(float v) {
#pragma unroll
  for (int m = 1; m < 64; m <<= 1) v += __shfl_xor(v, m, 64);
  return v;
}
__device__ __forceinline__ float softplus_f(float x) {
  return fmaxf(x, 0.0f) + log1pf(expf(-fabsf(x)));
}

#define DOT4(ACC, A, Bv) \
  ACC = fmaf((A).x, (Bv).x, fmaf((A).y, (Bv).y, fmaf((A).z, (Bv).z, fmaf((A).w, (Bv).w, ACC))))

// ---- s = sqrt(double-normalized softplus simplex), row-major (coalesced) ----
__global__ __launch_bounds__(256) void proj_kernel(const float* __restrict__ x,
                                                   float* __restrict__ s) {
  int wave = threadIdx.x >> 6, lane = threadIdx.x & 63;
  int row = blockIdx.x * 4 + wave;  // (b,t) flat
  float sp = softplus_f(x[row * D_ + lane]);
  float s1 = wave_sum(sp);
  float p = sp / (s1 + EPS);
  p = fmaxf(p, EPS);
  float s2 = wave_sum(p);
  s[row * D_ + lane] = sqrtf(p / (s2 + EPS));
}

// Stage 512x64 f32 (row-major, stride 64) global -> LDS with XOR swizzle.
// LDS physical (j, c4) holds logical (j, c4 ^ ((j>>2)&7)); reader of logical
// (j, d4) reads physical d4 ^ ((j>>2)&7).
__device__ __forceinline__ void stage512(const float* __restrict__ g,
                                         float* __restrict__ lds, int tid) {
#pragma unroll
  for (int h = 0; h < 2; ++h) {
    float4 v[8];
#pragma unroll
    for (int r = 0; r < 8; ++r) {
      int slot = (h * 8 + r) * 512 + tid;
      int j = slot >> 4, c4 = slot & 15;
      v[r] = *(const float4*)(g + j * 64 + ((c4 ^ ((j >> 2) & 7)) << 2));
    }
#pragma unroll
    for (int r = 0; r < 8; ++r) {
      int slot = (h * 8 + r) * 512 + tid;
      int j = slot >> 4, c4 = slot & 15;
      *(float4*)(lds + j * 64 + (c4 << 2)) = v[r];
    }
  }
}

// ---- fused iteration: logits + softmax + w@x + residual ----
// WRITE_S: also emit next-iter s.  DO_COV: also emit per-block cov/mean/kappa
// partials of the produced 8 output rows (fence-free p1 replacement).
// Block: 8 query rows, 512 threads (8 waves). Grid (64, B).
template <int WRITE_S, int DO_COV>
__global__ __launch_bounds__(512) void fiter_kernel(
    const float* __restrict__ s_g, const float* __restrict__ x_g,
    const float* __restrict__ rsp, float* __restrict__ xout,
    float* __restrict__ sout, float* __restrict__ covp,
    float* __restrict__ meanp, float* __restrict__ kappap) {
  int b = blockIdx.y, i0 = blockIdx.x * 8;
  int tid = threadIdx.x;
  int w = tid >> 6, lane = tid & 63;
  const float* sb = s_g + (size_t)b * (T_ * D_);
  const float* xb = x_g + (size_t)b * (T_ * D_);

  __shared__ __align__(16) float sx[512 * 64];   // s, then re-staged as x
  __shared__ __align__(16) float wlds[8 * 516];  // unnormalized exp weights
  __shared__ __align__(16) float redv[8 * 68];   // per-(row,d) PV partial
  __shared__ float redM[8][8];                   // rowmax partial [row][wave]
  __shared__ float redS[8][8];                   // exp-sum partial [row][wave]
  __shared__ float t8[8][68];                    // output rows (DO_COV)
  __shared__ float kred8[8];                     // row norms (DO_COV)

  stage512(sb, sx, tid);
  __syncthreads();

  // ---- phase L: logits S = -2*acos(clip(s_i . s_j)) for 8 rows x 64 cols ----
  int i4 = lane >> 4, j16 = lane & 15;
  int ia0 = i0 + 2 * i4;
  const float* A0 = sx + ia0 * 64;
  const float* A1 = A0 + 64;
  int mA0 = (ia0 >> 2) & 7, mA1 = ((ia0 + 1) >> 2) & 7;
  const float* Bp = sx + (w * 64 + 4 * j16) * 64;  // 4 consecutive j rows
  int mB = j16 & 7;

  float acc[2][4];
#pragma unroll
  for (int r = 0; r < 2; ++r)
#pragma unroll
    for (int c = 0; c < 4; ++c) acc[r][c] = 0.f;

#pragma unroll
  for (int d4 = 0; d4 < 16; ++d4) {
    float4 a0 = *(const float4*)(A0 + ((d4 ^ mA0) << 2));
    float4 a1 = *(const float4*)(A1 + ((d4 ^ mA1) << 2));
    int ob = (d4 ^ mB) << 2;
    float4 b0 = *(const float4*)(Bp + ob);
    float4 b1 = *(const float4*)(Bp + 64 + ob);
    float4 b2 = *(const float4*)(Bp + 128 + ob);
    float4 b3 = *(const float4*)(Bp + 192 + ob);
    DOT4(acc[0][0], a0, b0); DOT4(acc[0][1], a0, b1);
    DOT4(acc[0][2], a0, b2); DOT4(acc[0][3], a0, b3);
    DOT4(acc[1][0], a1, b0); DOT4(acc[1][1], a1, b1);
    DOT4(acc[1][2], a1, b2); DOT4(acc[1][3], a1, b3);
  }

  float S[2][4];
#pragma unroll
  for (int r = 0; r < 2; ++r)
#pragma unroll
    for (int c = 0; c < 4; ++c) {
      float inner = fminf(fmaxf(acc[r][c], -1.0f + 1e-6f), 1.0f - 1e-6f);
      S[r][c] = -2.0f * acosf(inner);
    }

  // per-wave rowmax over 64 cols (reduce across j16 = lane bits 0..3)
  float m0 = fmaxf(fmaxf(S[0][0], S[0][1]), fmaxf(S[0][2], S[0][3]));
  float m1 = fmaxf(fmaxf(S[1][0], S[1][1]), fmaxf(S[1][2], S[1][3]));
#pragma unroll
  for (int mm = 1; mm < 16; mm <<= 1) {
    m0 = fmaxf(m0, __shfl_xor(m0, mm, 64));
    m1 = fmaxf(m1, __shfl_xor(m1, mm, 64));
  }
  if (j16 == 0) { redM[2 * i4][w] = m0; redM[2 * i4 + 1][w] = m1; }
  __syncthreads();  // all waves done reading sx (s) + redM complete

  // re-stage x into the (now dead) s region; latency overlaps softmax finish
  stage512(xb, sx, tid);

  float M0 = redM[2 * i4][0], M1 = redM[2 * i4 + 1][0];
#pragma unroll
  for (int q = 1; q < 8; ++q) {
    M0 = fmaxf(M0, redM[2 * i4][q]);
    M1 = fmaxf(M1, redM[2 * i4 + 1][q]);
  }
  float e[2][4];
  float sl0 = 0.f, sl1 = 0.f;
#pragma unroll
  for (int c = 0; c < 4; ++c) {
    e[0][c] = __expf(S[0][c] - M0); sl0 += e[0][c];
    e[1][c] = __expf(S[1][c] - M1); sl1 += e[1][c];
  }
#pragma unroll
  for (int mm = 1; mm < 16; mm <<= 1) {
    sl0 += __shfl_xor(sl0, mm, 64);
    sl1 += __shfl_xor(sl1, mm, 64);
  }
  if (j16 == 0) { redS[2 * i4][w] = sl0; redS[2 * i4 + 1][w] = sl1; }
  int wb = w * 64 + 4 * j16;
#pragma unroll
  for (int r = 0; r < 2; ++r)
#pragma unroll
    for (int c = 0; c < 4; ++c) wlds[(2 * i4 + r) * 516 + wb + c] = e[r][c];
  __syncthreads();  // x staged + wlds/redS complete

  // ---- phase P: xa[i][d] = sum_j e[i][j] * x[j][d] ----
  int js = tid & 15, dg = (tid >> 4) & 15, ig = tid >> 8;
  int xcol = ((dg ^ (js & 7)) << 2);
  float pacc[4][4];
#pragma unroll
  for (int ii = 0; ii < 4; ++ii)
#pragma unroll
    for (int k = 0; k < 4; ++k) pacc[ii][k] = 0.f;

#pragma unroll 2
  for (int jj = 0; jj < 8; ++jj) {
    int jbase = jj * 64 + js * 4;
    const float* xr = sx + jbase * 64 + xcol;
    float4 x0 = *(const float4*)(xr);
    float4 x1 = *(const float4*)(xr + 64);
    float4 x2 = *(const float4*)(xr + 128);
    float4 x3 = *(const float4*)(xr + 192);
#pragma unroll
    for (int ii = 0; ii < 4; ++ii) {
      float4 wv = *(const float4*)(wlds + (4 * ig + ii) * 516 + jbase);
      pacc[ii][0] = fmaf(wv.x, x0.x, fmaf(wv.y, x1.x, fmaf(wv.z, x2.x, fmaf(wv.w, x3.x, pacc[ii][0]))));
      pacc[ii][1] = fmaf(wv.x, x0.y, fmaf(wv.y, x1.y, fmaf(wv.z, x2.y, fmaf(wv.w, x3.y, pacc[ii][1]))));
      pacc[ii][2] = fmaf(wv.x, x0.z, fmaf(wv.y, x1.z, fmaf(wv.z, x2.z, fmaf(wv.w, x3.z, pacc[ii][2]))));
      pacc[ii][3] = fmaf(wv.x, x0.w, fmaf(wv.y, x1.w, fmaf(wv.z, x2.w, fmaf(wv.w, x3.w, pacc[ii][3]))));
    }
  }
#pragma unroll
  for (int ii = 0; ii < 4; ++ii)
#pragma unroll
    for (int k = 0; k < 4; ++k) {
      float v = pacc[ii][k];
      v += __shfl_xor(v, 1, 64);
      v += __shfl_xor(v, 2, 64);
      v += __shfl_xor(v, 4, 64);
      v += __shfl_xor(v, 8, 64);
      pacc[ii][k] = v;
    }
  if (js == 0) {
#pragma unroll
    for (int ii = 0; ii < 4; ++ii)
      *(float4*)(redv + (4 * ig + ii) * 68 + (dg << 2)) =
          make_float4(pacc[ii][0], pacc[ii][1], pacc[ii][2], pacc[ii][3]);
  }
  __syncthreads();

  // ---- final: normalize, residual, write x (+ fused next-iter s / cov tile) ----
  {
    int row = w, d = lane;
    float ssum = 0.f;
#pragma unroll
    for (int q = 0; q < 8; ++q) ssum += redS[row][q];
    float xa = redv[row * 68 + d] / ssum;
    int ir = i0 + row;
    int mr = (ir >> 2) & 7;
    float xv = sx[ir * 64 + (((d >> 2) ^ mr) << 2) + (d & 3)];
    float c01 = 0.01f * rsp[0];
    float xn = 0.5f * (1.0f - c01) * xv + 0.5f * (1.0f + c01) * xa;
    size_t gi = ((size_t)(b * T_) + ir) * D_ + d;
    xout[gi] = xn;
    if (WRITE_S) {
      float sp = softplus_f(xn);
      float s1 = wave_sum(sp);
      float p = sp / (s1 + EPS);
      p = fmaxf(p, EPS);
      float s2 = wave_sum(p);
      sout[gi] = sqrtf(p / (s2 + EPS));
    }
    if (DO_COV) {
      t8[row][d] = xn;
      float ksq = wave_sum(xn * xn);
      if (lane == 0) kred8[row] = sqrtf(ksq);
    }
  }

  if (DO_COV) {
    __syncthreads();  // t8 + kred8 complete
    int blk = b * 64 + blockIdx.x;
    // cov partial: 512 threads = (dd 0..63) x (e8 0..7), 8 cells each, 8 rows
    int dd = tid >> 3, e8 = tid & 7;
    float ca[8];
#pragma unroll
    for (int k = 0; k < 8; ++k) ca[k] = 0.f;
#pragma unroll
    for (int r = 0; r < 8; ++r) {
      float xd = t8[r][dd];
      float4 v0 = *(const float4*)&t8[r][e8 * 8];
      float4 v1 = *(const float4*)&t8[r][e8 * 8 + 4];
      ca[0] = fmaf(xd, v0.x, ca[0]); ca[1] = fmaf(xd, v0.y, ca[1]);
      ca[2] = fmaf(xd, v0.z, ca[2]); ca[3] = fmaf(xd, v0.w, ca[3]);
      ca[4] = fmaf(xd, v1.x, ca[4]); ca[5] = fmaf(xd, v1.y, ca[5]);
      ca[6] = fmaf(xd, v1.z, ca[6]); ca[7] = fmaf(xd, v1.w, ca[7]);
    }
    float* cp = covp + (size_t)blk * 4096 + dd * 64 + e8 * 8;
    *(float4*)(cp) = make_float4(ca[0], ca[1], ca[2], ca[3]);
    *(float4*)(cp + 4) = make_float4(ca[4], ca[5], ca[6], ca[7]);
    if (tid < 64) {
      float ms = 0.f;
#pragma unroll
      for (int r = 0; r < 8; ++r) ms += t8[r][tid];
      meanp[blk * 64 + tid] = ms;
    }
    if (tid == 0) {
      float ks = 0.f;
#pragma unroll
      for (int r = 0; r < 8; ++r) ks += kred8[r];
      kappap[blk] = ks;
    }
  }
}

// ---- finalize: per-batch phi + kappa from 64 per-block partials ----
__global__ __launch_bounds__(1024) void finalize_kernel(
    const float* __restrict__ covp, const float* __restrict__ meanp,
    const float* __restrict__ kappap, float* __restrict__ out) {
  int b = blockIdx.x, tid = threadIdx.x;
  __shared__ float mu[64];
  __shared__ float var[64];
  __shared__ float phired[16];
  if (tid < 64) {
    float m = 0.f;
#pragma unroll
    for (int s = 0; s < 64; ++s) m += meanp[(b * 64 + s) * 64 + tid];
    mu[tid] = m * (1.0f / 512.0f);
  }
  __syncthreads();

  int dd = tid >> 4, e4 = tid & 15;  // 64 x 16, each thread 4 cells
  float acc[4] = {0.f, 0.f, 0.f, 0.f};
#pragma unroll
  for (int s = 0; s < 64; ++s) {
    float4 v = *(const float4*)(covp + (size_t)(b * 64 + s) * 4096 + dd * 64 + e4 * 4);
    acc[0] += v.x; acc[1] += v.y; acc[2] += v.z; acc[3] += v.w;
  }
  float mud = mu[dd];
#pragma unroll
  for (int k = 0; k < 4; ++k)
    acc[k] = acc[k] * (1.0f / 512.0f) - mud * mu[e4 * 4 + k];  // cov
  if (e4 == (dd >> 2)) var[dd] = fmaxf(acc[dd & 3], EPS);
  __syncthreads();

  float vd = var[dd];
  float psum = 0.f;
#pragma unroll
  for (int k = 0; k < 4; ++k) {
    int e = e4 * 4 + k;
    if (e == dd) continue;
    float denom = fmaxf(sqrtf(vd * var[e]), EPS);
    float cc = fminf(fmaxf(acc[k] / denom, -1.0f), 1.0f);
    psum += fabsf(cc);
  }
  psum = wave_sum(psum);
  if ((tid & 63) == 0) phired[tid >> 6] = psum;
  __syncthreads();
  if (tid == 0) {
    float ph = 0.f;
#pragma unroll
    for (int q = 0; q < 16; ++q) ph += phired[q];
    out[B_ * T_ * D_ + b] = ph * (1.0f / 4096.0f);
    float ks = 0.f;
#pragma unroll
    for (int s = 0; s < 64; ++s) ks += kappap[b * 64 + s];
    out[B_ * T_ * D_ + B_ + b] = ks * (1.0f / 512.0f);
  }
}

extern "C" void kernel_launch(void* const* d_in, const int* in_sizes, int n_in,
                              void* d_out, int out_size, void* d_ws, size_t ws_size,
                              hipStream_t stream) {
  const float* x0 = (const float*)d_in[0];
  const float* rs = (const float*)d_in[1];
  float* out = (float*)d_out;
  float* s0    = (float*)d_ws;                 // 131072 floats
  float* s1    = s0 + B_ * T_ * D_;            // 131072
  float* x1    = s1 + B_ * T_ * D_;            // 131072
  float* covp  = x1 + B_ * T_ * D_;            // 256*4096 = 1048576
  float* meanp = covp + 256 * 4096;            // 256*64
  float* kappap = meanp + 256 * 64;            // 256

  dim3 fgrd(64, 4);
  proj_kernel<<<(B_ * T_) / 4, 256, 0, stream>>>(x0, s0);
  fiter_kernel<1, 0><<<fgrd, 512, 0, stream>>>(s0, x0, rs, x1, s1, (float*)0,
                                               (float*)0, (float*)0);
  fiter_kernel<0, 1><<<fgrd, 512, 0, stream>>>(s1, x1, rs, out, (float*)0, covp,
                                               meanp, kappap);
  finalize_kernel<<<4, 1024, 0, stream>>>(covp, meanp, kappap, out);
}

// Round 7
// 92.262 us; speedup vs baseline: 2.2658x; 1.0813x over previous
//
#include <hip/hip_runtime.h>
#include <math.h>

#define B_ 4
#define T_ 512
#define D_ 64
#define EPS 1e-8f

__device__ __forceinline__ float wave_sum(float v) {
#pragma unroll
  for (int m = 1; m < 64; m <<= 1) v += __shfl_xor(v, m, 64);
  return v;
}
__device__ __forceinline__ float softplus_f(float x) {
  return fmaxf(x, 0.0f) + log1pf(expf(-fabsf(x)));
}

#define DOT4(ACC, A, Bv) \
  ACC = fmaf((A).x, (Bv).x, fmaf((A).y, (Bv).y, fmaf((A).z, (Bv).z, fmaf((A).w, (Bv).w, ACC))))

// ---- s = sqrt(double-normalized softplus simplex), row-major (coalesced) ----
__global__ __launch_bounds__(256) void proj_kernel(const float* __restrict__ x,
                                                   float* __restrict__ s) {
  int wave = threadIdx.x >> 6, lane = threadIdx.x & 63;
  int row = blockIdx.x * 4 + wave;  // (b,t) flat
  float sp = softplus_f(x[row * D_ + lane]);
  float s1 = wave_sum(sp);
  float p = sp / (s1 + EPS);
  p = fmaxf(p, EPS);
  float s2 = wave_sum(p);
  s[row * D_ + lane] = sqrtf(p / (s2 + EPS));
}

// Stage 512x64 f32 (row-major, stride 64) global -> LDS with XOR swizzle.
// LDS physical (j, c4) holds logical (j, c4 ^ ((j>>2)&7)); reader of logical
// (j, d4) reads physical d4 ^ ((j>>2)&7).
__device__ __forceinline__ void stage512(const float* __restrict__ g,
                                         float* __restrict__ lds, int tid) {
#pragma unroll
  for (int h = 0; h < 2; ++h) {
    float4 v[8];
#pragma unroll
    for (int r = 0; r < 8; ++r) {
      int slot = (h * 8 + r) * 512 + tid;
      int j = slot >> 4, c4 = slot & 15;
      v[r] = *(const float4*)(g + j * 64 + ((c4 ^ ((j >> 2) & 7)) << 2));
    }
#pragma unroll
    for (int r = 0; r < 8; ++r) {
      int slot = (h * 8 + r) * 512 + tid;
      int j = slot >> 4, c4 = slot & 15;
      *(float4*)(lds + j * 64 + (c4 << 2)) = v[r];
    }
  }
}

// ---- fused iteration: logits + softmax + w@x + residual ----
// WRITE_S: also emit next-iter s.  DO_COV: also emit per-block cov/mean/diag/
// kappa partials of the produced 8 output rows (fence-free p1 replacement),
// and zero the phi atomic accumulator for the NEXT dispatch (finalize).
// Block: 8 query rows, 512 threads (8 waves). Grid (64, B).
template <int WRITE_S, int DO_COV>
__global__ __launch_bounds__(512) void fiter_kernel(
    const float* __restrict__ s_g, const float* __restrict__ x_g,
    const float* __restrict__ rsp, float* __restrict__ xout,
    float* __restrict__ sout, float* __restrict__ covp,
    float* __restrict__ meanp, float* __restrict__ diagp,
    float* __restrict__ kappap) {
  int b = blockIdx.y, i0 = blockIdx.x * 8;
  int tid = threadIdx.x;
  int w = tid >> 6, lane = tid & 63;
  const float* sb = s_g + (size_t)b * (T_ * D_);
  const float* xb = x_g + (size_t)b * (T_ * D_);

  __shared__ __align__(16) float sx[512 * 64];   // s, then re-staged as x
  __shared__ __align__(16) float wlds[8 * 516];  // unnormalized exp weights
  __shared__ __align__(16) float redv[8 * 68];   // per-(row,d) PV partial
  __shared__ float redM[8][8];                   // rowmax partial [row][wave]
  __shared__ float redS[8][8];                   // exp-sum partial [row][wave]
  __shared__ float t8[8][68];                    // output rows (DO_COV)
  __shared__ float kred8[8];                     // row norms (DO_COV)

  if (DO_COV && blockIdx.x == 0 && tid == 0) xout[B_ * T_ * D_ + b] = 0.f;

  stage512(sb, sx, tid);
  __syncthreads();

  // ---- phase L: logits S = -2*acos(clip(s_i . s_j)) for 8 rows x 64 cols ----
  int i4 = lane >> 4, j16 = lane & 15;
  int ia0 = i0 + 2 * i4;
  const float* A0 = sx + ia0 * 64;
  const float* A1 = A0 + 64;
  int mA0 = (ia0 >> 2) & 7, mA1 = ((ia0 + 1) >> 2) & 7;
  const float* Bp = sx + (w * 64 + 4 * j16) * 64;  // 4 consecutive j rows
  int mB = j16 & 7;

  float acc[2][4];
#pragma unroll
  for (int r = 0; r < 2; ++r)
#pragma unroll
    for (int c = 0; c < 4; ++c) acc[r][c] = 0.f;

#pragma unroll
  for (int d4 = 0; d4 < 16; ++d4) {
    float4 a0 = *(const float4*)(A0 + ((d4 ^ mA0) << 2));
    float4 a1 = *(const float4*)(A1 + ((d4 ^ mA1) << 2));
    int ob = (d4 ^ mB) << 2;
    float4 b0 = *(const float4*)(Bp + ob);
    float4 b1 = *(const float4*)(Bp + 64 + ob);
    float4 b2 = *(const float4*)(Bp + 128 + ob);
    float4 b3 = *(const float4*)(Bp + 192 + ob);
    DOT4(acc[0][0], a0, b0); DOT4(acc[0][1], a0, b1);
    DOT4(acc[0][2], a0, b2); DOT4(acc[0][3], a0, b3);
    DOT4(acc[1][0], a1, b0); DOT4(acc[1][1], a1, b1);
    DOT4(acc[1][2], a1, b2); DOT4(acc[1][3], a1, b3);
  }

  float S[2][4];
#pragma unroll
  for (int r = 0; r < 2; ++r)
#pragma unroll
    for (int c = 0; c < 4; ++c) {
      float inner = fminf(fmaxf(acc[r][c], -1.0f + 1e-6f), 1.0f - 1e-6f);
      S[r][c] = -2.0f * acosf(inner);
    }

  // per-wave rowmax over 64 cols (reduce across j16 = lane bits 0..3)
  float m0 = fmaxf(fmaxf(S[0][0], S[0][1]), fmaxf(S[0][2], S[0][3]));
  float m1 = fmaxf(fmaxf(S[1][0], S[1][1]), fmaxf(S[1][2], S[1][3]));
#pragma unroll
  for (int mm = 1; mm < 16; mm <<= 1) {
    m0 = fmaxf(m0, __shfl_xor(m0, mm, 64));
    m1 = fmaxf(m1, __shfl_xor(m1, mm, 64));
  }
  if (j16 == 0) { redM[2 * i4][w] = m0; redM[2 * i4 + 1][w] = m1; }
  __syncthreads();  // all waves done reading sx (s) + redM complete

  // re-stage x into the (now dead) s region; latency overlaps softmax finish
  stage512(xb, sx, tid);

  float M0 = redM[2 * i4][0], M1 = redM[2 * i4 + 1][0];
#pragma unroll
  for (int q = 1; q < 8; ++q) {
    M0 = fmaxf(M0, redM[2 * i4][q]);
    M1 = fmaxf(M1, redM[2 * i4 + 1][q]);
  }
  float e[2][4];
  float sl0 = 0.f, sl1 = 0.f;
#pragma unroll
  for (int c = 0; c < 4; ++c) {
    e[0][c] = __expf(S[0][c] - M0); sl0 += e[0][c];
    e[1][c] = __expf(S[1][c] - M1); sl1 += e[1][c];
  }
#pragma unroll
  for (int mm = 1; mm < 16; mm <<= 1) {
    sl0 += __shfl_xor(sl0, mm, 64);
    sl1 += __shfl_xor(sl1, mm, 64);
  }
  if (j16 == 0) { redS[2 * i4][w] = sl0; redS[2 * i4 + 1][w] = sl1; }
  int wb = w * 64 + 4 * j16;
#pragma unroll
  for (int r = 0; r < 2; ++r)
#pragma unroll
    for (int c = 0; c < 4; ++c) wlds[(2 * i4 + r) * 516 + wb + c] = e[r][c];
  __syncthreads();  // x staged + wlds/redS complete

  // ---- phase P: xa[i][d] = sum_j e[i][j] * x[j][d] ----
  int js = tid & 15, dg = (tid >> 4) & 15, ig = tid >> 8;
  int xcol = ((dg ^ (js & 7)) << 2);
  float pacc[4][4];
#pragma unroll
  for (int ii = 0; ii < 4; ++ii)
#pragma unroll
    for (int k = 0; k < 4; ++k) pacc[ii][k] = 0.f;

#pragma unroll 2
  for (int jj = 0; jj < 8; ++jj) {
    int jbase = jj * 64 + js * 4;
    const float* xr = sx + jbase * 64 + xcol;
    float4 x0 = *(const float4*)(xr);
    float4 x1 = *(const float4*)(xr + 64);
    float4 x2 = *(const float4*)(xr + 128);
    float4 x3 = *(const float4*)(xr + 192);
#pragma unroll
    for (int ii = 0; ii < 4; ++ii) {
      float4 wv = *(const float4*)(wlds + (4 * ig + ii) * 516 + jbase);
      pacc[ii][0] = fmaf(wv.x, x0.x, fmaf(wv.y, x1.x, fmaf(wv.z, x2.x, fmaf(wv.w, x3.x, pacc[ii][0]))));
      pacc[ii][1] = fmaf(wv.x, x0.y, fmaf(wv.y, x1.y, fmaf(wv.z, x2.y, fmaf(wv.w, x3.y, pacc[ii][1]))));
      pacc[ii][2] = fmaf(wv.x, x0.z, fmaf(wv.y, x1.z, fmaf(wv.z, x2.z, fmaf(wv.w, x3.z, pacc[ii][2]))));
      pacc[ii][3] = fmaf(wv.x, x0.w, fmaf(wv.y, x1.w, fmaf(wv.z, x2.w, fmaf(wv.w, x3.w, pacc[ii][3]))));
    }
  }
#pragma unroll
  for (int ii = 0; ii < 4; ++ii)
#pragma unroll
    for (int k = 0; k < 4; ++k) {
      float v = pacc[ii][k];
      v += __shfl_xor(v, 1, 64);
      v += __shfl_xor(v, 2, 64);
      v += __shfl_xor(v, 4, 64);
      v += __shfl_xor(v, 8, 64);
      pacc[ii][k] = v;
    }
  if (js == 0) {
#pragma unroll
    for (int ii = 0; ii < 4; ++ii)
      *(float4*)(redv + (4 * ig + ii) * 68 + (dg << 2)) =
          make_float4(pacc[ii][0], pacc[ii][1], pacc[ii][2], pacc[ii][3]);
  }
  __syncthreads();

  // ---- final: normalize, residual, write x (+ fused next-iter s / cov tile) ----
  {
    int row = w, d = lane;
    float ssum = 0.f;
#pragma unroll
    for (int q = 0; q < 8; ++q) ssum += redS[row][q];
    float xa = redv[row * 68 + d] / ssum;
    int ir = i0 + row;
    int mr = (ir >> 2) & 7;
    float xv = sx[ir * 64 + (((d >> 2) ^ mr) << 2) + (d & 3)];
    float c01 = 0.01f * rsp[0];
    float xn = 0.5f * (1.0f - c01) * xv + 0.5f * (1.0f + c01) * xa;
    size_t gi = ((size_t)(b * T_) + ir) * D_ + d;
    xout[gi] = xn;
    if (WRITE_S) {
      float sp = softplus_f(xn);
      float s1 = wave_sum(sp);
      float p = sp / (s1 + EPS);
      p = fmaxf(p, EPS);
      float s2 = wave_sum(p);
      sout[gi] = sqrtf(p / (s2 + EPS));
    }
    if (DO_COV) {
      t8[row][d] = xn;
      float ksq = wave_sum(xn * xn);
      if (lane == 0) kred8[row] = sqrtf(ksq);
    }
  }

  if (DO_COV) {
    __syncthreads();  // t8 + kred8 complete
    int blk = b * 64 + blockIdx.x;
    // cov partial: 512 threads = (dd 0..63) x (e8 0..7), 8 cells each, 8 rows
    int dd = tid >> 3, e8 = tid & 7;
    float ca[8];
#pragma unroll
    for (int k = 0; k < 8; ++k) ca[k] = 0.f;
#pragma unroll
    for (int r = 0; r < 8; ++r) {
      float xd = t8[r][dd];
      float4 v0 = *(const float4*)&t8[r][e8 * 8];
      float4 v1 = *(const float4*)&t8[r][e8 * 8 + 4];
      ca[0] = fmaf(xd, v0.x, ca[0]); ca[1] = fmaf(xd, v0.y, ca[1]);
      ca[2] = fmaf(xd, v0.z, ca[2]); ca[3] = fmaf(xd, v0.w, ca[3]);
      ca[4] = fmaf(xd, v1.x, ca[4]); ca[5] = fmaf(xd, v1.y, ca[5]);
      ca[6] = fmaf(xd, v1.z, ca[6]); ca[7] = fmaf(xd, v1.w, ca[7]);
    }
    float* cp = covp + (size_t)blk * 4096 + dd * 64 + e8 * 8;
    *(float4*)(cp) = make_float4(ca[0], ca[1], ca[2], ca[3]);
    *(float4*)(cp + 4) = make_float4(ca[4], ca[5], ca[6], ca[7]);
    if (e8 == (dd >> 3)) diagp[blk * 64 + dd] = ca[dd & 7];  // raw sum x_d^2
    if (tid < 64) {
      float ms = 0.f;
#pragma unroll
      for (int r = 0; r < 8; ++r) ms += t8[r][tid];
      meanp[blk * 64 + tid] = ms;
    }
    if (tid == 0) {
      float ks = 0.f;
#pragma unroll
      for (int r = 0; r < 8; ++r) ks += kred8[r];
      kappap[blk] = ks;
    }
  }
}

// ---- finalize: separable phi over 16 slice-blocks per batch + kappa ----
// Grid (16 slices, B). Each block: mu/var from meanp/diagp (32 KB), then its
// 256-cell slice of cov summed over 64 partials (64 KB), phi partial via
// one atomicAdd (accumulator zeroed by fiter2 in the previous dispatch).
__global__ __launch_bounds__(256) void finalize_kernel(
    const float* __restrict__ covp, const float* __restrict__ meanp,
    const float* __restrict__ diagp, const float* __restrict__ kappap,
    float* __restrict__ out) {
  int g = blockIdx.x, b = blockIdx.y, tid = threadIdx.x;
  __shared__ float mred[4][64], dred[4][64];
  __shared__ float mu[64], var[64];
  __shared__ float phired[4];
  {
    int d = tid & 63, q = tid >> 6;
    float ms = 0.f, ds = 0.f;
#pragma unroll
    for (int s = 0; s < 16; ++s) {
      int sl = q * 16 + s;
      ms += meanp[(b * 64 + sl) * 64 + d];
      ds += diagp[(b * 64 + sl) * 64 + d];
    }
    mred[q][d] = ms; dred[q][d] = ds;
  }
  __syncthreads();
  if (tid < 64) {
    float m = (mred[0][tid] + mred[1][tid] + mred[2][tid] + mred[3][tid]) *
              (1.0f / 512.0f);
    float dsum = dred[0][tid] + dred[1][tid] + dred[2][tid] + dred[3][tid];
    mu[tid] = m;
    var[tid] = fmaxf(dsum * (1.0f / 512.0f) - m * m, EPS);
  }
  __syncthreads();

  int cell = g * 256 + tid;
  int dd = cell >> 6, e = cell & 63;
  float csum = 0.f;
#pragma unroll 4
  for (int s = 0; s < 64; ++s) csum += covp[(size_t)(b * 64 + s) * 4096 + cell];
  float cov = csum * (1.0f / 512.0f) - mu[dd] * mu[e];
  float psum = 0.f;
  if (e != dd) {
    float denom = fmaxf(sqrtf(var[dd] * var[e]), EPS);
    psum = fabsf(fminf(fmaxf(cov / denom, -1.0f), 1.0f));
  }
  psum = wave_sum(psum);
  if ((tid & 63) == 0) phired[tid >> 6] = psum;
  __syncthreads();
  if (tid == 0) {
    atomicAdd(&out[B_ * T_ * D_ + b],
              (phired[0] + phired[1] + phired[2] + phired[3]) * (1.0f / 4096.0f));
    if (g == 0) {
      float ks = 0.f;
#pragma unroll
      for (int s = 0; s < 64; ++s) ks += kappap[b * 64 + s];
      out[B_ * T_ * D_ + B_ + b] = ks * (1.0f / 512.0f);
    }
  }
}

extern "C" void kernel_launch(void* const* d_in, const int* in_sizes, int n_in,
                              void* d_out, int out_size, void* d_ws, size_t ws_size,
                              hipStream_t stream) {
  const float* x0 = (const float*)d_in[0];
  const float* rs = (const float*)d_in[1];
  float* out = (float*)d_out;
  float* s0    = (float*)d_ws;                 // 131072 floats
  float* s1    = s0 + B_ * T_ * D_;            // 131072
  float* x1    = s1 + B_ * T_ * D_;            // 131072
  float* covp  = x1 + B_ * T_ * D_;            // 256*4096 = 1048576
  float* meanp = covp + 256 * 4096;            // 256*64
  float* diagp = meanp + 256 * 64;             // 256*64
  float* kappap = diagp + 256 * 64;            // 256

  dim3 fgrd(64, 4);
  proj_kernel<<<(B_ * T_) / 4, 256, 0, stream>>>(x0, s0);
  fiter_kernel<1, 0><<<fgrd, 512, 0, stream>>>(s0, x0, rs, x1, s1, (float*)0,
                                               (float*)0, (float*)0, (float*)0);
  fiter_kernel<0, 1><<<fgrd, 512, 0, stream>>>(s1, x1, rs, out, (float*)0, covp,
                                               meanp, diagp, kappap);
  finalize_kernel<<<dim3(16, B_), 256, 0, stream>>>(covp, meanp, diagp, kappap,
                                                    out);
}